// Round 10
// baseline (492.443 us; speedup 1.0000x reference)
//
#include <hip/hip_runtime.h>
#include <hip/hip_bf16.h>

// ExpertODEEnsemble: E=8, D=64, H=512, B=32768.
// R25 = occupancy attack: 4 waves/SIMD, pure TLP.
//   Law from R15..R24: util proportional to waves/SIMD (1->21%, 2->38%);
//   invariant to sync topology, prefetch depth, waitcnt ownership. So: halve
//   the wave tile (M=64xN=64, acc=64 VGPR), run 2 blocks/CU x 8 waves
//   (launch_bounds(512,4) forces VGPR<=128 -> 16 waves/CU), delete all ILP
//   machinery (no prefetch/setprio/stagger) — TLP hides latency.
//   - 64-row tiles, 512 blocks. R21 sync skeleton VERBATIM (slot-8 rotation,
//     reverse group order, guard_grp/l4c/pub formulas); nt 4->2, SLOTB 8192.
//   - oacc eliminated: L4 does flag-ordered out-RMW per expert (kh0 writes
//     bias+sc*acc [e=0] / RMW [e>0], kh1 RMW after; out is L2-resident,
//     rows block-disjoint, same-CU L1 coherence, acyclic flag chain).
//   - prep_kernel + ws layout byte-identical to R15..R24.

typedef unsigned short ushort_t;
typedef unsigned int u32;
typedef unsigned long long u64;
typedef __attribute__((ext_vector_type(8))) short short8;
typedef __attribute__((ext_vector_type(4))) float floatx4;
typedef __attribute__((ext_vector_type(16))) float floatx16;
typedef __attribute__((ext_vector_type(4))) int intx4;

// ws layout (bytes); granule = 16 B = 8 bf16 along k (unchanged)
#define W1A_OFF 0u          // per e (65536 B): granule ((w*4+kc)*2+ol)*64+lane
#define W2A_OFF 524288u     // per e (524288B): granule ((w*32+kc)*2+ol)*64+lane
#define W3A_OFF 4718592u
#define W4A_OFF 8912896u    // per e (65536 B): granule (o4*32+kc)*64+lane
#define XB_OFF  9437184u    // x row-major bf16 [32768][64]
#define B1E_OFF 13631488u   // b1_eff fp32 [8][512]

// LDS (per 512-thread block): act 8 slots * 8192 = 65536; x 4 slabs * 2048;
// sync: l4c[8] pub[8] grp[8] okh0[4] okh1[4]
#define SLOTB 8192
#define X_OFF_L 65536
#define SYNC_OFF 73728
#define SMEM_SZ 73856

static __device__ __forceinline__ u32 pk2bf(float a, float b) {
  union { __hip_bfloat162 h; u32 u; } v;
  v.h = __float22bfloat162_rn(make_float2(a, b));
  return v.u;
}

static __device__ __forceinline__ float pade_tanh(float x) {
  // tanh x = x(945+105x^2+x^4)/(945+420x^2+15x^4); |err|<=1e-4 for |x|<=2
  float x2 = x * x;
  float num = __builtin_fmaf(x2, __builtin_fmaf(x2, 1.0f, 105.0f), 945.0f);
  float den = __builtin_fmaf(x2, __builtin_fmaf(x2, 15.0f, 420.0f), 945.0f);
  return x * num * __builtin_amdgcn_rcpf(den);
}

static __device__ __forceinline__ void ald16(const void* g, void* l) {
  __builtin_amdgcn_global_load_lds((__attribute__((address_space(1))) void*)g,
                                   (__attribute__((address_space(3))) void*)l,
                                   16, 0, 0);
}

static __device__ __forceinline__ floatx16 mfma32(short8 a, short8 b, floatx16 c) {
  return __builtin_amdgcn_mfma_f32_32x32x16_bf16(a, b, c, 0, 0, 0);
}

static __device__ __forceinline__ int slot8(int g, int b) {
  return ((g + b) & 7) * SLOTB;
}

// spin until *p >= tgt (LDS flag; all lanes read same addr -> broadcast)
static __device__ __forceinline__ void waitge(const int* p, int tgt) {
  while (*(volatile const int*)p < tgt) __builtin_amdgcn_s_sleep(1);
  __asm__ __volatile__("" ::: "memory");
}

// wait 4 contiguous flags >= tgt
static __device__ __forceinline__ void waitge4(const int* p, int tgt) {
  for (;;) {
    __asm__ __volatile__("" ::: "memory");
    intx4 v = *(const intx4*)p;
    if (v[0] >= tgt && v[1] >= tgt && v[2] >= tgt && v[3] >= tgt) break;
    __builtin_amdgcn_s_sleep(1);
  }
  __asm__ __volatile__("" ::: "memory");
}

// guard before overwriting own-input group (w+1)&7: for d=1..7 require
// grp[(w+d)&7] >= base + d  (verbatim R21)
static __device__ __forceinline__ void guard_grp(const int* grp, int w, int base) {
  int tg0 = base + ((0 - w - 1) & 7) + 1;
  int tg1 = base + ((1 - w - 1) & 7) + 1;
  int tg2 = base + ((2 - w - 1) & 7) + 1;
  int tg3 = base + ((3 - w - 1) & 7) + 1;
  int tg4 = base + ((4 - w - 1) & 7) + 1;
  int tg5 = base + ((5 - w - 1) & 7) + 1;
  int tg6 = base + ((6 - w - 1) & 7) + 1;
  int tg7 = base + ((7 - w - 1) & 7) + 1;
  for (;;) {
    __asm__ __volatile__("" ::: "memory");
    intx4 a = *(const intx4*)grp;
    intx4 b = *(const intx4*)(grp + 4);
    if (a[0] >= tg0 && a[1] >= tg1 && a[2] >= tg2 && a[3] >= tg3 &&
        b[0] >= tg4 && b[1] >= tg5 && b[2] >= tg6 && b[3] >= tg7) break;
    __builtin_amdgcn_s_sleep(1);
  }
  __asm__ __volatile__("" ::: "memory");
}

// publish after ds_writes
static __device__ __forceinline__ void bump(int* p, int lane) {
  __asm__ __volatile__("s_waitcnt lgkmcnt(0)" ::: "memory");
  if (lane == 0) atomicAdd(p, 1);
}
// signal reads-done (MFMA issue already forced ds_read completion)
static __device__ __forceinline__ void bump_sig(int* p, int lane) {
  __builtin_amdgcn_sched_barrier(0);
  if (lane == 0) atomicAdd(p, 1);
}
// publish after global stores (out-RMW chain)
static __device__ __forceinline__ void bump_vm(int* p, int lane) {
  __asm__ __volatile__("s_waitcnt vmcnt(0)" ::: "memory");
  if (lane == 0) atomicAdd(p, 1);
}

// ------ prep: byte-identical to R15..R24 ------
__global__ __launch_bounds__(256) void prep_kernel(
    const float* __restrict__ t, const float* __restrict__ x,
    const float* __restrict__ omega, const float* __restrict__ W1,
    const float* __restrict__ b1, const float* __restrict__ W2,
    const float* __restrict__ W3, const float* __restrict__ W4,
    char* __restrict__ ws) {
  int i = blockIdx.x * 256 + threadIdx.x;
  if (i < 32768) {                       // W1A
    int e = i >> 12, d = i & 4095;
    int lane = d & 63, q = d >> 6;
    int ol = q & 1, kc = (q >> 1) & 3, w = q >> 3;
    int outr = w * 64 + ol * 32 + (lane & 31);
    int kg = kc * 2 + (lane >> 5);
    const float* s = W1 + (e * 512 + outr) * 67 + kg * 8;
    ((intx4*)(ws + W1A_OFF))[i] = (intx4){
        (int)pk2bf(s[0], s[1]), (int)pk2bf(s[2], s[3]),
        (int)pk2bf(s[4], s[5]), (int)pk2bf(s[6], s[7])};
    return;
  }
  i -= 32768;
  if (i < 262144) {                      // W2A
    int e = i >> 15, d = i & 32767;
    int lane = d & 63, q = d >> 6;
    int ol = q & 1, kc = (q >> 1) & 31, w = q >> 6;
    int outr = w * 64 + ol * 32 + (lane & 31);
    int kg = kc * 2 + (lane >> 5);
    const floatx4* s = (const floatx4*)(W2 + ((e << 9) + outr) * 512 + (kg << 3));
    floatx4 lo = s[0], hi = s[1];
    ((intx4*)(ws + W2A_OFF))[i] = (intx4){
        (int)pk2bf(lo[0], lo[1]), (int)pk2bf(lo[2], lo[3]),
        (int)pk2bf(hi[0], hi[1]), (int)pk2bf(hi[2], hi[3])};
    return;
  }
  i -= 262144;
  if (i < 262144) {                      // W3A
    int e = i >> 15, d = i & 32767;
    int lane = d & 63, q = d >> 6;
    int ol = q & 1, kc = (q >> 1) & 31, w = q >> 6;
    int outr = w * 64 + ol * 32 + (lane & 31);
    int kg = kc * 2 + (lane >> 5);
    const floatx4* s = (const floatx4*)(W3 + ((e << 9) + outr) * 512 + (kg << 3));
    floatx4 lo = s[0], hi = s[1];
    ((intx4*)(ws + W3A_OFF))[i] = (intx4){
        (int)pk2bf(lo[0], lo[1]), (int)pk2bf(lo[2], lo[3]),
        (int)pk2bf(hi[0], hi[1]), (int)pk2bf(hi[2], hi[3])};
    return;
  }
  i -= 262144;
  if (i < 32768) {                       // W4A
    int e = i >> 12, d = i & 4095;
    int lane = d & 63, q = d >> 6;
    int kc = q & 31, o4 = q >> 5;
    int outr = o4 * 32 + (lane & 31);
    int kg = kc * 2 + (lane >> 5);
    const floatx4* s = (const floatx4*)(W4 + ((e << 6) + outr) * 512 + (kg << 3));
    floatx4 lo = s[0], hi = s[1];
    ((intx4*)(ws + W4A_OFF))[i] = (intx4){
        (int)pk2bf(lo[0], lo[1]), (int)pk2bf(lo[2], lo[3]),
        (int)pk2bf(hi[0], hi[1]), (int)pk2bf(hi[2], hi[3])};
    return;
  }
  i -= 32768;
  if (i < 262144) {                      // x -> bf16
    const floatx4* s = (const floatx4*)(x + i * 8);
    floatx4 lo = s[0], hi = s[1];
    ((intx4*)(ws + XB_OFF))[i] = (intx4){
        (int)pk2bf(lo[0], lo[1]), (int)pk2bf(lo[2], lo[3]),
        (int)pk2bf(hi[0], hi[1]), (int)pk2bf(hi[2], hi[3])};
    return;
  }
  i -= 262144;
  if (i < 4096) {                        // b1_eff
    float tv = t[0];
    int e = i >> 9;
    float om = omega[e];
    ((float*)(ws + B1E_OFF))[i] = b1[i] + tv * W1[i * 67 + 64]
        + sinf(om * tv) * W1[i * 67 + 65] + cosf(om * tv) * W1[i * 67 + 66];
  }
}

// slab (2048 B, 64 rows): nt*1024 + (k16half*32 + r31)*16 + q1*8 (write);
// read: chunk nt at slab + nt*1024 + lane*16.

static __device__ __forceinline__ void epi_write2(
    floatx16 acc[2][2], char* __restrict__ act, int wbyte, int r31, int q1) {
#pragma unroll
  for (int ol = 0; ol < 2; ++ol) {
#pragma unroll
    for (int g = 0; g < 4; ++g) {
      int ko = ol * 4 + g;
      char* base = act + wbyte + (ko >> 1) * 2048
                   + (((ko & 1) * 32 + r31) << 4) + q1 * 8;
#pragma unroll
      for (int nt = 0; nt < 2; ++nt) {
        float v0 = pade_tanh(acc[ol][nt][4 * g + 0]);
        float v1 = pade_tanh(acc[ol][nt][4 * g + 1]);
        float v2 = pade_tanh(acc[ol][nt][4 * g + 2]);
        float v3 = pade_tanh(acc[ol][nt][4 * g + 3]);
        u32 lo = pk2bf(v0, v1), hi = pk2bf(v2, v3);
        *(u64*)(base + nt * 1024) = ((u64)hi << 32) | lo;
      }
    }
  }
}

// 8-MFMA burst over a kc pair: A at ap (+1024 ol, +2048 kc), B at bp
// (+1024 nt, +2048 kc). No prefetch: TLP hides latency.
static __device__ __forceinline__ void burst2(
    floatx16 acc[2][2], const char* ap, const char* bp) {
  short8 a00 = *(const short8*)(ap);
  short8 a01 = *(const short8*)(ap + 1024);
  short8 a10 = *(const short8*)(ap + 2048);
  short8 a11 = *(const short8*)(ap + 3072);
  short8 b00 = *(const short8*)(bp);
  short8 b01 = *(const short8*)(bp + 1024);
  short8 b10 = *(const short8*)(bp + 2048);
  short8 b11 = *(const short8*)(bp + 3072);
  acc[0][0] = mfma32(a00, b00, acc[0][0]);
  acc[0][1] = mfma32(a00, b01, acc[0][1]);
  acc[1][0] = mfma32(a01, b00, acc[1][0]);
  acc[1][1] = mfma32(a01, b01, acc[1][1]);
  acc[0][0] = mfma32(a10, b10, acc[0][0]);
  acc[0][1] = mfma32(a10, b11, acc[0][1]);
  acc[1][0] = mfma32(a11, b10, acc[1][0]);
  acc[1][1] = mfma32(a11, b11, acc[1][1]);
}

static __device__ __forceinline__ void acc_init(
    floatx16 acc[2][2], const float* bias, int w, int q1) {
#pragma unroll
  for (int ol = 0; ol < 2; ++ol) {
    int fe0 = w * 64 + ol * 32 + 4 * q1;
#pragma unroll
    for (int g = 0; g < 4; ++g) {
      floatx4 bv = *(const floatx4*)(bias + fe0 + 8 * g);
#pragma unroll
      for (int nt = 0; nt < 2; ++nt) {
        acc[ol][nt][4 * g + 0] = bv[0];
        acc[ol][nt][4 * g + 1] = bv[1];
        acc[ol][nt][4 * g + 2] = bv[2];
        acc[ol][nt][4 * g + 3] = bv[3];
      }
    }
  }
}

// L1: B from x in LDS (4 slabs = 1 group); guard vs L4(e-1) readers.
static __device__ __forceinline__ void mlp_l1(
    char* __restrict__ act, const char* __restrict__ xreg,
    int* pub, int* l4c, int lane, int w, int q1, int r31,
    const char* __restrict__ Abase, const float* __restrict__ bias,
    int wbyte, int e) {
  const int voff = lane * 16;
  const char* ap = Abase + w * 8192 + voff;
  floatx16 acc[2][2];
  acc_init(acc, bias, w, q1);
#pragma unroll
  for (int js = 0; js < 2; ++js)
    burst2(acc, ap + js * 4096, xreg + js * 4096 + voff);
  // overwrite guard: victim = L3(e-1) out group (w+1)&7, read by L4(e-1)
  if (e > 0) waitge4(l4c + ((((w + 1) & 7) >> 2) << 2), e);
  epi_write2(acc, act, wbyte, r31, q1);
  bump(pub + w, lane);
}

// L2/L3: B from act slots, reverse rotation (g = w, w-1, ... mod 8).
static __device__ __forceinline__ void mlp_mid(
    char* __restrict__ act, int* pub, int* grp, int lane, int w, int q1, int r31,
    const char* __restrict__ Abase, const float* __restrict__ bias,
    int pub_tgt, int rbase, int wbyte, int gbase) {
  const int voff = lane * 16;
  const char* spA = Abase + w * 65536 + voff;
  floatx16 acc[2][2];
  acc_init(acc, bias, w, q1);
#pragma unroll 1
  for (int i = 0; i < 8; ++i) {
    int g = (w - i) & 7;
    if (i > 0) waitge(pub + g, pub_tgt);   // i=0: own group, program order
    const char* gb = act + slot8(g, rbase) + voff;
    const char* ap = spA + g * 8192;
#pragma unroll
    for (int js = 0; js < 2; ++js)
      burst2(acc, ap + js * 4096, gb + js * 4096);
    bump_sig(grp + w, lane);               // group g consumed
  }
  guard_grp(grp, w, gbase);                // victim = own input group (w+1)&7
  epi_write2(acc, act, wbyte, r31, q1);
  bump(pub + w, lane);
}

extern "C" __global__ __launch_bounds__(512, 4) void fused_kernel(
    const char* __restrict__ ws, const float* __restrict__ b2,
    const float* __restrict__ b3, const float* __restrict__ b4,
    const float* __restrict__ ew, float* __restrict__ out) {
  extern __shared__ char smem[];
  char* act = smem;
  char* xreg = smem + X_OFF_L;
  int* l4c = (int*)(smem + SYNC_OFF);
  int* pub = l4c + 8;
  int* grp = l4c + 16;
  int* okh0 = l4c + 24;
  int* okh1 = l4c + 28;

  const int t = threadIdx.x, lane = t & 63, w = t >> 6;   // 8 waves
  const int q1 = lane >> 5, r31 = lane & 31;
  const int row0 = blockIdx.x << 6;      // 64-row tile, 512 blocks (2/CU)
  const int voff = lane * 16;

  if (t < 32) ((int*)(smem + SYNC_OFF))[t] = 0;

  // stage x: 8 units of 1KB; wave w: x-slab w>>1, nt w&1
  {
    const ushort_t* xb = (const ushort_t*)(ws + XB_OFF);
    int v = w >> 1, nt = w & 1;
    ald16(xb + (row0 + nt * 32 + r31) * 64 + (2 * v + q1) * 8,
          xreg + v * 2048 + nt * 1024);
  }
  __syncthreads();                       // x staged + flags zeroed

  // L4 piece: o4 = w&1 (32 feats), nt4 = (w>>1)&1 (32 rows), kh = w>>2 (K=256)
  const int o4 = w & 1, nt4 = (w >> 1) & 1, kh = w >> 2, pp = w & 3;
  const int row_l4 = row0 + nt4 * 32 + r31;

  for (int e = 0; e < 8; ++e) {
    int b1s = (3 * e + 1) & 7;           // L1-out frame (= L2 input frame)
    int b2s = (3 * e + 2) & 7;           // L2-out frame
    int b3s = (3 * e + 3) & 7;           // L3-out frame (= L4 input frame)

    mlp_l1(act, xreg, pub, l4c, lane, w, q1, r31,
           (const char*)ws + W1A_OFF + e * 65536,
           (const float*)(ws + B1E_OFF) + e * 512, slot8(w, b1s), e);
    mlp_mid(act, pub, grp, lane, w, q1, r31,
            (const char*)ws + W2A_OFF + e * 524288, b2 + e * 512,
            3 * e + 1, b1s, slot8(w, b2s), 16 * e);
    mlp_mid(act, pub, grp, lane, w, q1, r31,
            (const char*)ws + W3A_OFF + e * 524288, b3 + e * 512,
            3 * e + 2, b2s, slot8(w, b3s), 16 * e + 8);

    // L4: piece 32 feats x 32 rows x K-half kh (groups 4kh..4kh+3)
    {
      const char* apW4 = (const char*)ws + W4A_OFF + e * 65536
                         + o4 * 32768 + voff;
      floatx16 acc4 = {};
#pragma unroll 1
      for (int gl = 0; gl < 4; ++gl) {
        int g = 4 * kh + gl;
        waitge(pub + g, 3 * e + 3);
        const char* gb = act + slot8(g, b3s) + nt4 * 1024 + voff;
#pragma unroll
        for (int s = 0; s < 4; ++s) {
          short8 a = *(const short8*)(apW4 + (4 * g + s) * 1024);
          short8 b = *(const short8*)(gb + s * 2048);
          acc4 = mfma32(a, b, acc4);
        }
      }
      bump_sig(l4c + w, lane);           // L4(e) act-reads done

      // out-RMW, kh0 -> kh1 flag-ordered (rows block-disjoint; same-CU L1)
      const float sc = ew[row_l4 * 8 + e];
      float* orow = out + (size_t)row_l4 * 64 + o4 * 32;
      if (kh == 0) {
        if (e > 0) waitge(okh1 + pp, e);     // kh1(e-1) stores landed
        const float* bp = b4 + e * 64 + o4 * 32;
#pragma unroll
        for (int g2 = 0; g2 < 4; ++g2) {
          floatx4 bv = *(const floatx4*)(bp + 8 * g2 + 4 * q1);
          float* dst = orow + 8 * g2 + 4 * q1;
          floatx4 cur = (e > 0) ? *(const floatx4*)dst
                                : (floatx4){0.f, 0.f, 0.f, 0.f};
          floatx4 v = {cur[0] + sc * (acc4[4 * g2 + 0] + bv[0]),
                       cur[1] + sc * (acc4[4 * g2 + 1] + bv[1]),
                       cur[2] + sc * (acc4[4 * g2 + 2] + bv[2]),
                       cur[3] + sc * (acc4[4 * g2 + 3] + bv[3])};
          *(floatx4*)dst = v;
        }
        bump_vm(okh0 + pp, lane);
      } else {
        waitge(okh0 + pp, e + 1);            // kh0(e) stores landed
#pragma unroll
        for (int g2 = 0; g2 < 4; ++g2) {
          float* dst = orow + 8 * g2 + 4 * q1;
          floatx4 cur = *(const floatx4*)dst;
          floatx4 v = {cur[0] + sc * acc4[4 * g2 + 0],
                       cur[1] + sc * acc4[4 * g2 + 1],
                       cur[2] + sc * acc4[4 * g2 + 2],
                       cur[3] + sc * acc4[4 * g2 + 3]};
          *(floatx4*)dst = v;
        }
        bump_vm(okh1 + pp, lane);
      }
    }
  }
}

extern "C" void kernel_launch(void* const* d_in, const int* in_sizes, int n_in,
                              void* d_out, int out_size, void* d_ws, size_t ws_size,
                              hipStream_t stream) {
  const float* t  = (const float*)d_in[0];
  const float* x  = (const float*)d_in[1];
  const float* ew = (const float*)d_in[2];
  const float* om = (const float*)d_in[3];
  const float* W1 = (const float*)d_in[4];
  const float* b1 = (const float*)d_in[5];
  const float* W2 = (const float*)d_in[6];
  const float* b2 = (const float*)d_in[7];
  const float* W3 = (const float*)d_in[8];
  const float* b3 = (const float*)d_in[9];
  const float* W4 = (const float*)d_in[10];
  const float* b4 = (const float*)d_in[11];
  char* ws = (char*)d_ws;
  float* out = (float*)d_out;
  (void)in_sizes; (void)n_in; (void)ws_size; (void)out_size;

  static int smem_set = 0;
  if (!smem_set) {
    hipFuncSetAttribute((const void*)fused_kernel,
                        hipFuncAttributeMaxDynamicSharedMemorySize, SMEM_SZ);
    smem_set = 1;
  }
  // out fully written by fused_kernel (kh0 e=0 writes, later RMW) — no memset
  prep_kernel<<<3344, 256, 0, stream>>>(t, x, om, W1, b1, W2, W3, W4, ws);
  fused_kernel<<<512, 512, SMEM_SZ, stream>>>(ws, b2, b3, b4, ew, out);
}

// Round 11
// 420.879 us; speedup vs baseline: 1.1700x; 1.1700x over previous
//
#include <hip/hip_runtime.h>
#include <hip/hip_bf16.h>

// ExpertODEEnsemble: E=8, D=64, H=512, B=32768.
// R26 = R21 + XCD expert-order decorrelation (single change).
//   Invariant from R15..R25: matrix-busy time constant (~140us-equiv);
//   wall insensitive to sync/prefetch/waitcnt/occupancy. Theory: L2/L3
//   slice hotspot — all 256 blocks stream the SAME expert's weights in
//   phase; hot slices serve 256 readers, queueing defeats prefetch (R22/
//   R24 nulls) and extra waves (R25). Fix: block starts its expert loop
//   at e0 = blockIdx.x & 7 (XCD round-robin idiom) -> 8 different experts
//   in flight chip-wide, per-XCD working set ~1.2MB (L2-resident), slice
//   load spread 8x.
//   Mechanics: sync counters + slot frames keyed on ITERATION i (monotone,
//   identical arithmetic); addresses/bias/ew keyed on expert e=(e0+i)&7.
//   oacc sum order-independent. Everything else byte-identical to R21.

typedef unsigned short ushort_t;
typedef unsigned int u32;
typedef unsigned long long u64;
typedef __attribute__((ext_vector_type(8))) short short8;
typedef __attribute__((ext_vector_type(4))) float floatx4;
typedef __attribute__((ext_vector_type(16))) float floatx16;
typedef __attribute__((ext_vector_type(4))) int intx4;

// ws layout (bytes); granule = 16 B = 8 bf16 along k (unchanged from R15)
#define W1A_OFF 0u          // per e (65536 B): granule ((w*4+kc)*2+ol)*64+lane
#define W2A_OFF 524288u     // per e (524288B): granule ((w*32+kc)*2+ol)*64+lane
#define W3A_OFF 4718592u
#define W4A_OFF 8912896u    // per e (65536 B): granule (o4*32+kc)*64+lane
#define XB_OFF  9437184u    // x row-major bf16 [32768][64]
#define B1E_OFF 13631488u   // b1_eff fp32 [8][512]

// LDS: 8 slot-groups * 4 slabs * 4096 = 131072; x 4 slabs * 4096 = 16384;
// sync: l4c[8], pub[8], grp[8]
#define SLOTB 16384
#define X_OFF_L 131072
#define SYNC_OFF 147456
#define SMEM_SZ 147552

static __device__ __forceinline__ u32 pk2bf(float a, float b) {
  union { __hip_bfloat162 h; u32 u; } v;
  v.h = __float22bfloat162_rn(make_float2(a, b));
  return v.u;
}

static __device__ __forceinline__ float pade_tanh(float x) {
  // tanh x = x(945+105x^2+x^4)/(945+420x^2+15x^4); |err|<=1e-4 for |x|<=2
  float x2 = x * x;
  float num = __builtin_fmaf(x2, __builtin_fmaf(x2, 1.0f, 105.0f), 945.0f);
  float den = __builtin_fmaf(x2, __builtin_fmaf(x2, 15.0f, 420.0f), 945.0f);
  return x * num * __builtin_amdgcn_rcpf(den);
}

static __device__ __forceinline__ void ald16(const void* g, void* l) {
  __builtin_amdgcn_global_load_lds((__attribute__((address_space(1))) void*)g,
                                   (__attribute__((address_space(3))) void*)l,
                                   16, 0, 0);
}

static __device__ __forceinline__ floatx16 mfma32(short8 a, short8 b, floatx16 c) {
  return __builtin_amdgcn_mfma_f32_32x32x16_bf16(a, b, c, 0, 0, 0);
}

// byte offset of slot for group g with layer base b (b = layer index & 7)
static __device__ __forceinline__ int slot8(int g, int b) {
  return ((g + b) & 7) * SLOTB;
}

// spin until *p >= tgt (LDS flag; all lanes read same addr -> broadcast)
static __device__ __forceinline__ void waitge(const int* p, int tgt) {
  while (*(volatile const int*)p < tgt) __builtin_amdgcn_s_sleep(1);
  __asm__ __volatile__("" ::: "memory");
}

// wait 4 contiguous flags >= tgt (16B vector read; clobber forces re-read)
static __device__ __forceinline__ void waitge4(const int* p, int tgt) {
  for (;;) {
    __asm__ __volatile__("" ::: "memory");
    intx4 v = *(const intx4*)p;
    if (v[0] >= tgt && v[1] >= tgt && v[2] >= tgt && v[3] >= tgt) break;
    __builtin_amdgcn_s_sleep(1);
  }
  __asm__ __volatile__("" ::: "memory");
}

// guard before overwriting own-input group (w+1)&7: for d=1..7 require
// grp[(w+d)&7] >= base + d (reader at step d-1 of its reverse rotation done).
static __device__ __forceinline__ void guard_grp(const int* grp, int w, int base) {
  int tg0 = base + ((0 - w - 1) & 7) + 1;
  int tg1 = base + ((1 - w - 1) & 7) + 1;
  int tg2 = base + ((2 - w - 1) & 7) + 1;
  int tg3 = base + ((3 - w - 1) & 7) + 1;
  int tg4 = base + ((4 - w - 1) & 7) + 1;
  int tg5 = base + ((5 - w - 1) & 7) + 1;
  int tg6 = base + ((6 - w - 1) & 7) + 1;
  int tg7 = base + ((7 - w - 1) & 7) + 1;
  for (;;) {
    __asm__ __volatile__("" ::: "memory");
    intx4 a = *(const intx4*)grp;
    intx4 b = *(const intx4*)(grp + 4);
    if (a[0] >= tg0 && a[1] >= tg1 && a[2] >= tg2 && a[3] >= tg3 &&
        b[0] >= tg4 && b[1] >= tg5 && b[2] >= tg6 && b[3] >= tg7) break;
    __builtin_amdgcn_s_sleep(1);
  }
  __asm__ __volatile__("" ::: "memory");
}

// publish after ds_writes: drain own LDS ops, then one lane bumps
static __device__ __forceinline__ void bump(int* p, int lane) {
  __asm__ __volatile__("s_waitcnt lgkmcnt(0)" ::: "memory");
  if (lane == 0) atomicAdd(p, 1);
}

// signal "reads done": consuming MFMAs already forced completion of the
// protected ds_reads; sched_barrier pins the atomic after them.
static __device__ __forceinline__ void bump_sig(int* p, int lane) {
  __builtin_amdgcn_sched_barrier(0);
  if (lane == 0) atomicAdd(p, 1);
}

// ------ prep: thread == dest granule (lane-fastest) -> coalesced writes ------
// (byte-identical to R15..R25)
__global__ __launch_bounds__(256) void prep_kernel(
    const float* __restrict__ t, const float* __restrict__ x,
    const float* __restrict__ omega, const float* __restrict__ W1,
    const float* __restrict__ b1, const float* __restrict__ W2,
    const float* __restrict__ W3, const float* __restrict__ W4,
    char* __restrict__ ws) {
  int i = blockIdx.x * 256 + threadIdx.x;
  if (i < 32768) {                       // W1A: d=((w*4+kc)*2+ol)*64+lane
    int e = i >> 12, d = i & 4095;
    int lane = d & 63, q = d >> 6;
    int ol = q & 1, kc = (q >> 1) & 3, w = q >> 3;
    int outr = w * 64 + ol * 32 + (lane & 31);
    int kg = kc * 2 + (lane >> 5);
    const float* s = W1 + (e * 512 + outr) * 67 + kg * 8;   // stride 67: scalar
    ((intx4*)(ws + W1A_OFF))[i] = (intx4){
        (int)pk2bf(s[0], s[1]), (int)pk2bf(s[2], s[3]),
        (int)pk2bf(s[4], s[5]), (int)pk2bf(s[6], s[7])};
    return;
  }
  i -= 32768;
  if (i < 262144) {                      // W2A: d=((w*32+kc)*2+ol)*64+lane
    int e = i >> 15, d = i & 32767;
    int lane = d & 63, q = d >> 6;
    int ol = q & 1, kc = (q >> 1) & 31, w = q >> 6;
    int outr = w * 64 + ol * 32 + (lane & 31);
    int kg = kc * 2 + (lane >> 5);
    const floatx4* s = (const floatx4*)(W2 + ((e << 9) + outr) * 512 + (kg << 3));
    floatx4 lo = s[0], hi = s[1];
    ((intx4*)(ws + W2A_OFF))[i] = (intx4){
        (int)pk2bf(lo[0], lo[1]), (int)pk2bf(lo[2], lo[3]),
        (int)pk2bf(hi[0], hi[1]), (int)pk2bf(hi[2], hi[3])};
    return;
  }
  i -= 262144;
  if (i < 262144) {                      // W3A
    int e = i >> 15, d = i & 32767;
    int lane = d & 63, q = d >> 6;
    int ol = q & 1, kc = (q >> 1) & 31, w = q >> 6;
    int outr = w * 64 + ol * 32 + (lane & 31);
    int kg = kc * 2 + (lane >> 5);
    const floatx4* s = (const floatx4*)(W3 + ((e << 9) + outr) * 512 + (kg << 3));
    floatx4 lo = s[0], hi = s[1];
    ((intx4*)(ws + W3A_OFF))[i] = (intx4){
        (int)pk2bf(lo[0], lo[1]), (int)pk2bf(lo[2], lo[3]),
        (int)pk2bf(hi[0], hi[1]), (int)pk2bf(hi[2], hi[3])};
    return;
  }
  i -= 262144;
  if (i < 32768) {                       // W4A: d=(o4*32+kc)*64+lane
    int e = i >> 12, d = i & 4095;
    int lane = d & 63, q = d >> 6;
    int kc = q & 31, o4 = q >> 5;
    int outr = o4 * 32 + (lane & 31);
    int kg = kc * 2 + (lane >> 5);
    const floatx4* s = (const floatx4*)(W4 + ((e << 6) + outr) * 512 + (kg << 3));
    floatx4 lo = s[0], hi = s[1];
    ((intx4*)(ws + W4A_OFF))[i] = (intx4){
        (int)pk2bf(lo[0], lo[1]), (int)pk2bf(lo[2], lo[3]),
        (int)pk2bf(hi[0], hi[1]), (int)pk2bf(hi[2], hi[3])};
    return;
  }
  i -= 32768;
  if (i < 262144) {                      // x -> bf16 (coalesced both ways)
    const floatx4* s = (const floatx4*)(x + i * 8);
    floatx4 lo = s[0], hi = s[1];
    ((intx4*)(ws + XB_OFF))[i] = (intx4){
        (int)pk2bf(lo[0], lo[1]), (int)pk2bf(lo[2], lo[3]),
        (int)pk2bf(hi[0], hi[1]), (int)pk2bf(hi[2], hi[3])};
    return;
  }
  i -= 262144;
  if (i < 4096) {                        // b1_eff
    float tv = t[0];
    int e = i >> 9;
    float om = omega[e];
    ((float*)(ws + B1E_OFF))[i] = b1[i] + tv * W1[i * 67 + 64]
        + sinf(om * tv) * W1[i * 67 + 65] + cosf(om * tv) * W1[i * 67 + 66];
  }
}

// slab (4096 B): nt*1024 + ((k16half)*32 + r31)*16 + q1*8 (write side);
// read side: chunk nt at +nt*1024 + lane*16 — identical pair to R15.

static __device__ __forceinline__ void epi_write(
    floatx16 acc[2][4], char* __restrict__ act, int wbyte, int r31, int q1) {
#pragma unroll
  for (int ol = 0; ol < 2; ++ol) {
#pragma unroll
    for (int g = 0; g < 4; ++g) {
      int ko = ol * 4 + g;
      char* base = act + wbyte + (ko >> 1) * 4096
                   + (((ko & 1) * 32 + r31) << 4) + q1 * 8;
#pragma unroll
      for (int nt = 0; nt < 4; ++nt) {
        float v0 = pade_tanh(acc[ol][nt][4 * g + 0]);
        float v1 = pade_tanh(acc[ol][nt][4 * g + 1]);
        float v2 = pade_tanh(acc[ol][nt][4 * g + 2]);
        float v3 = pade_tanh(acc[ol][nt][4 * g + 3]);
        u32 lo = pk2bf(v0, v1), hi = pk2bf(v2, v3);
        *(u64*)(base + nt * 1024) = ((u64)hi << 32) | lo;
      }
    }
  }
}

// L1: B from x in LDS (4 slabs); guard vs L4(prev iter) readers.
// iter = loop iteration (monotone sync key); Abase/bias carry the expert.
static __device__ __forceinline__ void mlp_l1(
    char* __restrict__ act, const char* __restrict__ xreg,
    int* pub, int* l4c, int lane, int w, int q1, int r31,
    const char* __restrict__ Abase, const float* __restrict__ bias,
    int wbyte, int iter) {
  const int voff = lane * 16;
  const char* ap = Abase + w * 8192 + voff;

  floatx16 acc[2][4];
#pragma unroll
  for (int ol = 0; ol < 2; ++ol) {
    int fe0 = w * 64 + ol * 32 + 4 * q1;
#pragma unroll
    for (int g = 0; g < 4; ++g) {
      floatx4 bv = *(const floatx4*)(bias + fe0 + 8 * g);
#pragma unroll
      for (int nt = 0; nt < 4; ++nt) {
        acc[ol][nt][4 * g + 0] = bv[0];
        acc[ol][nt][4 * g + 1] = bv[1];
        acc[ol][nt][4 * g + 2] = bv[2];
        acc[ol][nt][4 * g + 3] = bv[3];
      }
    }
  }
  const char* xb0 = xreg + voff;
  short8 b0 = *(const short8*)(xb0);
  short8 b1v = *(const short8*)(xb0 + 1024);
  short8 b2 = *(const short8*)(xb0 + 2048);
  short8 b3 = *(const short8*)(xb0 + 3072);
  short8 a0 = *(const short8*)(ap);
  short8 a1 = *(const short8*)(ap + 1024);

#pragma unroll
  for (int j = 0; j < 4; ++j) {
    int jn = (j < 3) ? (j + 1) : 3;                // clamp (dead at j=3)
    const char* xn = xreg + jn * 4096 + voff;
    const char* apn = (j < 3) ? (ap + 2048) : ap;
    short8 an0 = *(const short8*)(apn);
    short8 an1 = *(const short8*)(apn + 1024);
    short8 bn0 = *(const short8*)(xn);
    short8 bn1 = *(const short8*)(xn + 1024);
    short8 bn2 = *(const short8*)(xn + 2048);
    short8 bn3 = *(const short8*)(xn + 3072);
    __builtin_amdgcn_s_setprio(1);
    acc[0][0] = mfma32(a0, b0, acc[0][0]);
    acc[0][1] = mfma32(a0, b1v, acc[0][1]);
    acc[0][2] = mfma32(a0, b2, acc[0][2]);
    acc[0][3] = mfma32(a0, b3, acc[0][3]);
    acc[1][0] = mfma32(a1, b0, acc[1][0]);
    acc[1][1] = mfma32(a1, b1v, acc[1][1]);
    acc[1][2] = mfma32(a1, b2, acc[1][2]);
    acc[1][3] = mfma32(a1, b3, acc[1][3]);
    __builtin_amdgcn_s_setprio(0);
    a0 = an0; a1 = an1;
    b0 = bn0; b1v = bn1; b2 = bn2; b3 = bn3;
    ap = apn;
  }
  // overwrite guard: victim = L3(iter-1) output group (w+1)&7, read by
  // L4(iter-1) waves of quad ((w+1)&7)>>2 — each bumps l4c once per iter.
  if (iter > 0) waitge4(l4c + ((((w + 1) & 7) >> 2) << 2), iter);
  epi_write(acc, act, wbyte, r31, q1);
  bump(pub + w, lane);
}

// L2/L3: B from act slots, reverse rotation (g = w, w-1, ... mod 8).
static __device__ __forceinline__ void mlp_mid(
    char* __restrict__ act, int* pub, int* grp, int lane, int w, int q1, int r31,
    const char* __restrict__ Abase, const float* __restrict__ bias,
    int pub_tgt, int rbase, int wbyte, int gbase) {
  const int voff = lane * 16;
  const char* spA = Abase + w * 65536 + voff;

  floatx16 acc[2][4];
#pragma unroll
  for (int ol = 0; ol < 2; ++ol) {
    int fe0 = w * 64 + ol * 32 + 4 * q1;
#pragma unroll
    for (int g = 0; g < 4; ++g) {
      floatx4 bv = *(const floatx4*)(bias + fe0 + 8 * g);
#pragma unroll
      for (int nt = 0; nt < 4; ++nt) {
        acc[ol][nt][4 * g + 0] = bv[0];
        acc[ol][nt][4 * g + 1] = bv[1];
        acc[ol][nt][4 * g + 2] = bv[2];
        acc[ol][nt][4 * g + 3] = bv[3];
      }
    }
  }
  // prologue: own group (g=w) slab 0 — self-published in program order.
  const char* gb = act + slot8(w, rbase) + voff;
  const char* ap = spA + (4 * w) * 2048;
  short8 b0 = *(const short8*)(gb);
  short8 b1v = *(const short8*)(gb + 1024);
  short8 b2 = *(const short8*)(gb + 2048);
  short8 b3 = *(const short8*)(gb + 3072);
  short8 a0 = *(const short8*)(ap);
  short8 a1 = *(const short8*)(ap + 1024);

#pragma unroll 1
  for (int i = 0; i < 8; ++i) {
#pragma unroll
    for (int j = 0; j < 4; ++j) {
      const char* apn;
      const char* gbn = gb;
      const char* bsl;
      if (j < 3) {
        apn = ap + 2048;
        bsl = gb + (j + 1) * 4096;
      } else if (i < 7) {
        int g2 = (w - i - 1) & 7;
        waitge(pub + g2, pub_tgt);       // steady-state: long since satisfied
        gbn = act + slot8(g2, rbase) + voff;
        apn = spA + (4 * g2) * 2048;
        bsl = gbn;
      } else {
        apn = ap; bsl = gb;              // dead prefetch, in-bounds
      }
      short8 an0 = *(const short8*)(apn);
      short8 an1 = *(const short8*)(apn + 1024);
      short8 bn0 = *(const short8*)(bsl);
      short8 bn1 = *(const short8*)(bsl + 1024);
      short8 bn2 = *(const short8*)(bsl + 2048);
      short8 bn3 = *(const short8*)(bsl + 3072);
      __builtin_amdgcn_s_setprio(1);
      acc[0][0] = mfma32(a0, b0, acc[0][0]);
      acc[0][1] = mfma32(a0, b1v, acc[0][1]);
      acc[0][2] = mfma32(a0, b2, acc[0][2]);
      acc[0][3] = mfma32(a0, b3, acc[0][3]);
      acc[1][0] = mfma32(a1, b0, acc[1][0]);
      acc[1][1] = mfma32(a1, b1v, acc[1][1]);
      acc[1][2] = mfma32(a1, b2, acc[1][2]);
      acc[1][3] = mfma32(a1, b3, acc[1][3]);
      __builtin_amdgcn_s_setprio(0);
      a0 = an0; a1 = an1;
      b0 = bn0; b1v = bn1; b2 = bn2; b3 = bn3;
      ap = apn; gb = gbn;
    }
    bump_sig(grp + w, lane);             // group (w-i)&7 of this layer consumed
  }

  // overwrite guard: victim = own input group (w+1)&7; readers = this layer.
  guard_grp(grp, w, gbase);
  epi_write(acc, act, wbyte, r31, q1);
  bump(pub + w, lane);
}

extern "C" __global__ __launch_bounds__(512) void fused_kernel(
    const char* __restrict__ ws, const float* __restrict__ b2,
    const float* __restrict__ b3, const float* __restrict__ b4,
    const float* __restrict__ ew, float* __restrict__ out) {
  extern __shared__ char smem[];
  char* act = smem;
  char* xreg = smem + X_OFF_L;
  int* l4c = (int*)(smem + SYNC_OFF);
  int* pub = l4c + 8;
  int* grp = l4c + 16;

  const int t = threadIdx.x, lane = t & 63, w = t >> 6;   // 8 waves
  const int q1 = lane >> 5, r31 = lane & 31;
  const int row0 = blockIdx.x << 7;      // 128-row tile, 256 blocks (1/CU)
  const int voff = lane * 16;

  if (t < 24) ((int*)(smem + SYNC_OFF))[t] = 0;

  // stage x: 16 units of 1KB; unit u: x-slab u>>2, nt u&3 (stride 4096)
  const ushort_t* xb = (const ushort_t*)(ws + XB_OFF);
#pragma unroll
  for (int s = 0; s < 2; ++s) {
    int u = w + 8 * s, v = u >> 2, nt = u & 3;
    ald16(xb + (row0 + nt * 32 + r31) * 64 + (2 * v + q1) * 8,
          xreg + v * 4096 + nt * 1024);
  }
  __syncthreads();                       // x staged + flags zeroed

  // seed the inter-wave stagger: wave 7 first, ~450 cyc per index.
  for (int i = (7 - w) * 7; i > 0; --i) __builtin_amdgcn_s_sleep(1);

  const int rt = w & 3, kh = w >> 2;     // L4: row-tile, K-half
  const int row_l4 = row0 + rt * 32 + r31;
  const int e0 = blockIdx.x & 7;         // XCD expert-order decorrelation
  floatx16 oacc[2] = {};

  for (int it = 0; it < 8; ++it) {
    const int e = (e0 + it) & 7;         // expert for addresses/bias/ew
    int b1s = (3 * it + 1) & 7;          // L1-out frame (= L2 input frame)
    int b2s = (3 * it + 2) & 7;          // L2-out frame
    int b3s = (3 * it + 3) & 7;          // L3-out frame (= L4 input frame)

    mlp_l1(act, xreg, pub, l4c, lane, w, q1, r31,
           (const char*)ws + W1A_OFF + e * 65536,
           (const float*)(ws + B1E_OFF) + e * 512, slot8(w, b1s), it);
    mlp_mid(act, pub, grp, lane, w, q1, r31,
            (const char*)ws + W2A_OFF + e * 524288, b2 + e * 512,
            3 * it + 1, b1s, slot8(w, b2s), 16 * it);
    mlp_mid(act, pub, grp, lane, w, q1, r31,
            (const char*)ws + W3A_OFF + e * 524288, b3 + e * 512,
            3 * it + 2, b2s, slot8(w, b3s), 16 * it + 8);

    // L4: M=64 (both o4), N=32 (rows rt), K-half kh; groups descending;
    // no act writes.
    {
      const char* spA4 = (const char*)ws + W4A_OFF + e * 65536 + voff;
      const float sc = ew[row_l4 * 8 + e];
      floatx16 acc4[2] = {};
      int g = 4 * kh + 3;
      waitge(pub + g, 3 * it + 3);
      const char* agb = spA4 + (4 * g) * 1024;
      const char* gb = act + slot8(g, b3s) + rt * 1024 + voff;
      short8 a0 = *(const short8*)(agb);
      short8 a1 = *(const short8*)(agb + 32768);
      short8 b = *(const short8*)(gb);
#pragma unroll 1
      for (int gl = 0; gl < 4; ++gl) {
#pragma unroll
        for (int j = 0; j < 4; ++j) {
          const char* agn = agb;
          const char* gbn = gb;
          const char* asl; const char* bsl;
          if (j < 3) {
            asl = agb + (j + 1) * 1024;
            bsl = gb + (j + 1) * 4096;
          } else if (gl < 3) {
            int g2 = g - 1;
            waitge(pub + g2, 3 * it + 3);
            agn = spA4 + (4 * g2) * 1024;
            gbn = act + slot8(g2, b3s) + rt * 1024 + voff;
            asl = agn; bsl = gbn;
          } else {
            asl = agb; bsl = gb;         // dead prefetch, in-bounds
          }
          short8 an0 = *(const short8*)(asl);
          short8 an1 = *(const short8*)(asl + 32768);
          short8 bn = *(const short8*)(bsl);
          __builtin_amdgcn_s_setprio(1);
          acc4[0] = mfma32(a0, b, acc4[0]);
          acc4[1] = mfma32(a1, b, acc4[1]);
          __builtin_amdgcn_s_setprio(0);
          a0 = an0; a1 = an1; b = bn;
          agb = agn; gb = gbn;
        }
        g = g - 1;
      }
      bump_sig(l4c + w, lane);           // L4(it) done: unblocks overwrites
      if (kh == 0) {
        const float* bp = b4 + e * 64;
#pragma unroll
        for (int ol = 0; ol < 2; ++ol) {
          int fe0 = ol * 32 + 4 * q1;
#pragma unroll
          for (int g2 = 0; g2 < 4; ++g2) {
            floatx4 bv = *(const floatx4*)(bp + fe0 + 8 * g2);
            oacc[ol][4 * g2 + 0] += sc * (acc4[ol][4 * g2 + 0] + bv[0]);
            oacc[ol][4 * g2 + 1] += sc * (acc4[ol][4 * g2 + 1] + bv[1]);
            oacc[ol][4 * g2 + 2] += sc * (acc4[ol][4 * g2 + 2] + bv[2]);
            oacc[ol][4 * g2 + 3] += sc * (acc4[ol][4 * g2 + 3] + bv[3]);
          }
        }
      } else {
#pragma unroll
        for (int ol = 0; ol < 2; ++ol)
#pragma unroll
          for (int i = 0; i < 16; ++i) oacc[ol][i] += sc * acc4[ol][i];
      }
    }
  }

  // final: merge K-half partners (w, w+4) via LDS (act dead), plain stores
  __syncthreads();
  if (kh == 1) {
#pragma unroll
    for (int ol = 0; ol < 2; ++ol)
#pragma unroll
      for (int g = 0; g < 4; ++g) {
        floatx4 p = {oacc[ol][4 * g + 0], oacc[ol][4 * g + 1],
                     oacc[ol][4 * g + 2], oacc[ol][4 * g + 3]};
        *(floatx4*)(act + rt * 8192 + ol * 4096 + g * 1024 + lane * 16) = p;
      }
  }
  __syncthreads();
  if (kh == 0) {
    float* orow = out + (size_t)row_l4 * 64;
#pragma unroll
    for (int ol = 0; ol < 2; ++ol)
#pragma unroll
      for (int g = 0; g < 4; ++g) {
        floatx4 p = *(const floatx4*)(act + rt * 8192 + ol * 4096 + g * 1024 + lane * 16);
        floatx4 v = {oacc[ol][4 * g + 0] + p[0], oacc[ol][4 * g + 1] + p[1],
                     oacc[ol][4 * g + 2] + p[2], oacc[ol][4 * g + 3] + p[3]};
        *(floatx4*)(orow + ol * 32 + 8 * g + 4 * q1) = v;
      }
  }
}

extern "C" void kernel_launch(void* const* d_in, const int* in_sizes, int n_in,
                              void* d_out, int out_size, void* d_ws, size_t ws_size,
                              hipStream_t stream) {
  const float* t  = (const float*)d_in[0];
  const float* x  = (const float*)d_in[1];
  const float* ew = (const float*)d_in[2];
  const float* om = (const float*)d_in[3];
  const float* W1 = (const float*)d_in[4];
  const float* b1 = (const float*)d_in[5];
  const float* W2 = (const float*)d_in[6];
  const float* b2 = (const float*)d_in[7];
  const float* W3 = (const float*)d_in[8];
  const float* b3 = (const float*)d_in[9];
  const float* W4 = (const float*)d_in[10];
  const float* b4 = (const float*)d_in[11];
  char* ws = (char*)d_ws;
  float* out = (float*)d_out;
  (void)in_sizes; (void)n_in; (void)ws_size; (void)out_size;

  static int smem_set = 0;
  if (!smem_set) {
    hipFuncSetAttribute((const void*)fused_kernel,
                        hipFuncAttributeMaxDynamicSharedMemorySize, SMEM_SZ);
    smem_set = 1;
  }
  // no memset: fused_kernel writes every element of out with plain stores
  prep_kernel<<<3344, 256, 0, stream>>>(t, x, om, W1, b1, W2, W3, W4, ws);
  fused_kernel<<<256, 512, SMEM_SZ, stream>>>(ws, b2, b3, b4, ew, out);
}